// Round 14
// baseline (73.414 us; speedup 1.0000x reference)
//
#include <hip/hip_runtime.h>

#define NBLOCKS 4096
#define WPB 4
#define BLOCK 256

typedef __attribute__((ext_vector_type(8))) short sh8;
typedef __attribute__((ext_vector_type(4))) float f32x4;

__device__ __forceinline__ float frcp(float x) { return __builtin_amdgcn_rcpf(x); }

__device__ __forceinline__ float fast_tanh(float x) {
    float e = __expf(2.f * x);
    return 1.f - 2.f * frcp(e + 1.f);
}

// swizzled bf16 index into a [rows][64] LDS array (row stride = 32 dwords).
__device__ __forceinline__ int zidx(int m, int u) {
    return (((m << 5) + (((u >> 1) ^ ((m & 7) << 2)))) << 1) + (u & 1);
}

__device__ __forceinline__ sh8 ldfrag(const unsigned short* base, int row, int g, int kt) {
    const int dw = (row << 5) + ((((kt << 4) + (g << 2))) ^ ((row & 7) << 2));
    return *(const sh8*)(base + (dw << 1));
}

__device__ __forceinline__ unsigned short rtn_bf16(float x) {
    unsigned u = __float_as_uint(x);
    u += 0x7FFFu + ((u >> 16) & 1u);
    return (unsigned short)(u >> 16);
}

__device__ __forceinline__ unsigned cvt_pk_bf16(float lo, float hi) {
    unsigned r;
    asm("v_cvt_pk_bf16_f32 %0, %1, %2" : "=v"(r) : "v"(lo), "v"(hi));
    return r;
}

__device__ __forceinline__ void wsplit(float x, unsigned short& h, unsigned short& l) {
    const unsigned ub = __float_as_uint(x);
    const unsigned hb = ub & 0xffff0000u;
    const float lf = x - __uint_as_float(hb);
    h = (unsigned short)(hb >> 16);
    l = (unsigned short)(__float_as_uint(lf) >> 16);
}

__device__ __forceinline__ void stage15s(unsigned short* zh, const float* z, int lane) {
    #pragma unroll
    for (int m = 0; m < 14; m += 2) {
        const unsigned r = cvt_pk_bf16(z[m], z[m + 1]);
        zh[zidx(m, lane)] = (unsigned short)r;
        zh[zidx(m + 1, lane)] = (unsigned short)(r >> 16);
    }
    zh[zidx(14, lane)] = (unsigned short)cvt_pk_bf16(z[14], z[14]);
}

__device__ __forceinline__ void jet_nl(const float* a, float bias, float* z) {
    const float a0v = a[0] + bias;
    const float y = fast_tanh(a0v);
    const float D = 1.f - y * y;
    const float m2 = -2.f * y * D;
    z[0] = y;
    z[1] = D * a[1]; z[2] = D * a[2]; z[3] = D * a[3]; z[4] = D * a[4];
    z[5] = D * a[5] + m2 * a[1] * a[1];
    z[6] = D * a[6] + m2 * a[1] * a[2];
    z[7] = D * a[7] + m2 * a[1] * a[3];
    z[8] = D * a[8] + m2 * a[1] * a[4];
    z[9] = D * a[9] + m2 * a[2] * a[2];
    z[10] = D * a[10] + m2 * a[2] * a[3];
    z[11] = D * a[11] + m2 * a[2] * a[4];
    z[12] = D * a[12] + m2 * a[3] * a[3];
    z[13] = D * a[13] + m2 * a[3] * a[4];
    z[14] = D * a[14] + m2 * a[4] * a[4];
}

#define WAITLDS asm volatile("" ::: "memory")

// ============ kernel 1: MLP jet pipeline -> 15 scalars/pt into ws ============
// PRECISION LEDGER: state/W2/W3 = single RNE bf16; W1 = f32; W4 = hi/lo bf16.
// absmax 6144 vs threshold 1.024e4 -- no further precision cuts.
// REGISTER PLAN: base ~52 + Whf 64 + W4 16 ~= 132 VGPR. (256,3) cap ~170:
// no spill expected (R5/R6 spilled at caps 102/128 needing ~150). Spill
// signature = WRITE_SIZE >> 4 MB.
// LDS PLAN: one 20 KB pool. Preamble: wlds[2][4096] + w4lds[2048] (weights,
// read into registers). Main loop: first 16 KB re-used as per-wave zS[4][2048].
// __syncthreads after the register loads orders the alias switch.
__global__ __launch_bounds__(BLOCK, 3) void jet_kernel(
    const float* __restrict__ coords,
    const float* __restrict__ gW1, const float* __restrict__ gb1,
    const float* __restrict__ gW2, const float* __restrict__ gb2,
    const float* __restrict__ gW3, const float* __restrict__ gb3,
    const float* __restrict__ gW4,
    float* __restrict__ ws, int B)
{
    __shared__ __align__(16) unsigned short pool[10240];   // 20 KB

    unsigned short* wlds0 = pool;           // [4096] W2 (preamble only)
    unsigned short* wlds1 = pool + 4096;    // [4096] W3 (preamble only)
    unsigned short* w4lds = pool + 8192;    // [2048] W4 frags (preamble only)

    const int wv = threadIdx.x >> 6;
    const int lane = threadIdx.x & 63;
    const int n15 = lane & 15;
    const int g = lane >> 4;

    // ---- preamble: stage weights in LDS, pull all fragments to registers ----
    for (int e = threadIdx.x; e < 4096; e += BLOCK) {
        const int o = e & 63, i = e >> 6;
        const int ix = zidx(o, i);
        wlds0[ix] = rtn_bf16(gW2[i * 64 + o]);
        wlds1[ix] = rtn_bf16(gW3[i * 64 + o]);
    }
    #pragma unroll
    for (int kt = 0; kt < 2; ++kt) {
        sh8 bh, bl;
        #pragma unroll
        for (int e = 0; e < 8; ++e) {
            const float v = (n15 == 0) ? gW4[kt * 32 + g * 8 + e] : 0.f;
            unsigned short h, l;
            wsplit(v, h, l);
            bh[e] = (short)h;
            bl[e] = (short)l;
        }
        *(sh8*)(w4lds + kt * 512 + (lane << 3)) = bh;
        *(sh8*)(w4lds + (2 + kt) * 512 + (lane << 3)) = bl;
    }
    __syncthreads();
    sh8 Whf[2][4][2];
    #pragma unroll
    for (int L = 0; L < 2; ++L)
        #pragma unroll
        for (int nt = 0; nt < 4; ++nt)
            #pragma unroll
            for (int kt = 0; kt < 2; ++kt)
                Whf[L][nt][kt] = ldfrag(L ? wlds1 : wlds0, nt * 16 + n15, g, kt);
    const sh8 Bh0 = *(const sh8*)(w4lds + 0 * 512 + (lane << 3));
    const sh8 Bh1 = *(const sh8*)(w4lds + 1 * 512 + (lane << 3));
    const sh8 Bw0 = *(const sh8*)(w4lds + 2 * 512 + (lane << 3));
    const sh8 Bw1 = *(const sh8*)(w4lds + 3 * 512 + (lane << 3));
    __syncthreads();   // all weight reads retired before pool is re-used as zS

    // per-wave 4 KB state region (aliases the weight-staging LDS)
    unsigned short* zbase = pool + wv * 2048;
    float* cb = (float*)zbase;
    // A-row 15 garbage (alias residue) confined to C row 15: never read.

    const float w1c0 = gW1[0 * 64 + lane];
    const float w1c1 = gW1[1 * 64 + lane];
    const float w1c2 = gW1[2 * 64 + lane];
    const float w1c3 = gW1[3 * 64 + lane];
    const float b1c = gb1[lane], b2c = gb2[lane], b3c = gb3[lane];

    const int wid = blockIdx.x * WPB + wv;
    const int nw = NBLOCKS * WPB;

    for (int p = 2 * wid; p < B; p += 2 * nw) {
        float4 c4[2];
        c4[0] = reinterpret_cast<const float4*>(coords)[p];
        c4[1] = reinterpret_cast<const float4*>(coords)[p + 1];

        #pragma unroll
        for (int pt = 0; pt < 2; ++pt) {
            float z[15];
            const float u = b1c + c4[pt].x * w1c0 + c4[pt].y * w1c1 + c4[pt].z * w1c2 + c4[pt].w * w1c3;
            const float y = fast_tanh(u);
            const float D = 1.f - y * y;
            const float m2 = -2.f * y * D;
            z[0] = y;
            z[1] = D * w1c0; z[2] = D * w1c1; z[3] = D * w1c2; z[4] = D * w1c3;
            z[5] = m2 * w1c0 * w1c0; z[6] = m2 * w1c0 * w1c1; z[7] = m2 * w1c0 * w1c2; z[8] = m2 * w1c0 * w1c3;
            z[9] = m2 * w1c1 * w1c1; z[10] = m2 * w1c1 * w1c2; z[11] = m2 * w1c1 * w1c3;
            z[12] = m2 * w1c2 * w1c2; z[13] = m2 * w1c2 * w1c3; z[14] = m2 * w1c3 * w1c3;
            stage15s(zbase + pt * 1024, z, lane);
        }
        WAITLDS;

        #pragma unroll
        for (int LL = 0; LL < 2; ++LL) {
            sh8 A0[2], A1[2];
            #pragma unroll
            for (int pt = 0; pt < 2; ++pt) {
                A0[pt] = ldfrag(zbase + pt * 1024, n15, g, 0);
                A1[pt] = ldfrag(zbase + pt * 1024, n15, g, 1);
            }
            WAITLDS;   // frag reads ordered before scatter clobbers the alias
            f32x4 acc[2][4];
            #pragma unroll
            for (int nt = 0; nt < 4; ++nt) {
                #pragma unroll
                for (int pt = 0; pt < 2; ++pt) {
                    f32x4 a0 = {0.f, 0.f, 0.f, 0.f};
                    a0 = __builtin_amdgcn_mfma_f32_16x16x32_bf16(A0[pt], Whf[LL][nt][0], a0, 0, 0, 0);
                    a0 = __builtin_amdgcn_mfma_f32_16x16x32_bf16(A1[pt], Whf[LL][nt][1], a0, 0, 0, 0);
                    acc[pt][nt] = a0;
                }
            }
            float z0[15], z1[15];
            {
                #pragma unroll
                for (int nt = 0; nt < 4; ++nt) {
                    const int u = nt * 16 + n15;
                    *(f32x4*)(cb + u * 16 + ((g << 2) ^ (u & 12))) = acc[0][nt];
                }
                WAITLDS;
                float a[15];
                #pragma unroll
                for (int c = 0; c < 4; ++c) {
                    const f32x4 r = *(const f32x4*)(cb + lane * 16 + ((c << 2) ^ (lane & 12)));
                    #pragma unroll
                    for (int t = 0; t < 4; ++t)
                        if (c * 4 + t < 15) a[c * 4 + t] = r[t];
                }
                WAITLDS;
                jet_nl(a, LL ? b3c : b2c, z0);
            }
            {
                #pragma unroll
                for (int nt = 0; nt < 4; ++nt) {
                    const int u = nt * 16 + n15;
                    *(f32x4*)(cb + u * 16 + ((g << 2) ^ (u & 12))) = acc[1][nt];
                }
                WAITLDS;
                float a[15];
                #pragma unroll
                for (int c = 0; c < 4; ++c) {
                    const f32x4 r = *(const f32x4*)(cb + lane * 16 + ((c << 2) ^ (lane & 12)));
                    #pragma unroll
                    for (int t = 0; t < 4; ++t)
                        if (c * 4 + t < 15) a[c * 4 + t] = r[t];
                }
                WAITLDS;
                jet_nl(a, LL ? b3c : b2c, z1);
            }
            stage15s(zbase, z0, lane);
            stage15s(zbase + 1024, z1, lane);
            WAITLDS;
        }

        // final layer (64 -> 1) as MFMA reduce with register W4 frags
        #pragma unroll
        for (int pt = 0; pt < 2; ++pt) {
            const sh8 A0 = ldfrag(zbase + pt * 1024, n15, g, 0);
            const sh8 A1 = ldfrag(zbase + pt * 1024, n15, g, 1);
            f32x4 r = {0.f, 0.f, 0.f, 0.f};
            r = __builtin_amdgcn_mfma_f32_16x16x32_bf16(A0, Bh0, r, 0, 0, 0);
            r = __builtin_amdgcn_mfma_f32_16x16x32_bf16(A1, Bh1, r, 0, 0, 0);
            r = __builtin_amdgcn_mfma_f32_16x16x32_bf16(A0, Bw0, r, 0, 0, 0);
            r = __builtin_amdgcn_mfma_f32_16x16x32_bf16(A1, Bw1, r, 0, 0, 0);
            // row m = g*4+reg, col 0 = lanes n15==0: 4 lanes store 4 jets each
            if (n15 == 0)
                reinterpret_cast<f32x4*>(ws)[(p + pt) * 4 + g] = r;
        }
        WAITLDS;   // frag reads ordered before next iteration's stage15s clobbers
    }
}

// ============ kernel 2: per-point Einstein epilogue, all-register ============
__global__ void einstein_epilogue(
    const float* __restrict__ coords,
    const float* __restrict__ ws,
    const float* __restrict__ gb4,
    float* __restrict__ out, int B)
{
    const int p = blockIdx.x * blockDim.x + threadIdx.x;
    if (p >= B) return;
    const float4 c4 = reinterpret_cast<const float4*>(coords)[p];
    const float cr = c4.y, cth = c4.z;
    const f32x4 r0 = reinterpret_cast<const f32x4*>(ws)[p * 4 + 0];
    const f32x4 r1 = reinterpret_cast<const f32x4*>(ws)[p * 4 + 1];
    const f32x4 r2 = reinterpret_cast<const f32x4*>(ws)[p * 4 + 2];
    const f32x4 r3 = reinterpret_cast<const f32x4*>(ws)[p * 4 + 3];
    const float f = r0[0] + gb4[0];
    float fj[4] = {r0[1], r0[2], r0[3], r1[0]};
    float fk[4][4];
    fk[0][0] = r1[1]; fk[0][1] = fk[1][0] = r1[2]; fk[0][2] = fk[2][0] = r1[3]; fk[0][3] = fk[3][0] = r2[0];
    fk[1][1] = r2[1]; fk[1][2] = fk[2][1] = r2[2]; fk[1][3] = fk[3][1] = r2[3];
    fk[2][2] = r3[0]; fk[2][3] = fk[3][2] = r3[1]; fk[3][3] = r3[2];

    float S, C;
    __sincosf(cth, &S, &C);
    const float E = __expf(f);
    const float r2v = cr * cr, S2 = S * S;
    const float GI1 = frcp(E), GI2 = frcp(r2v), GI3 = GI2 * frcp(S2);
    const float GIa[4] = {-1.f, GI1, GI2, GI3};

    float dg[4][4] = {};
    #pragma unroll
    for (int b = 0; b < 4; ++b) dg[1][b] = E * fj[b];
    dg[2][1] = 2.f * cr;
    dg[3][1] = 2.f * cr * S2;
    dg[3][2] = 2.f * r2v * S * C;
    const float ddrr3 = 2.f * S2, ddrth3 = 4.f * cr * S * C, ddthth3 = 2.f * r2v * (C * C - S2);

    auto dd = [&](int a, int b, int l) -> float {
        if (a == 1) return E * (fj[b] * fj[l] + fk[b][l]);
        if (a == 2) return (b == 1 && l == 1) ? 2.f : 0.f;
        if (a == 3) {
            if (b == 1 && l == 1) return ddrr3;
            if ((b == 1 && l == 2) || (b == 2 && l == 1)) return ddrth3;
            if (b == 2 && l == 2) return ddthth3;
        }
        return 0.f;
    };

    float Gm[4][4][4];
    #pragma unroll
    for (int i = 0; i < 4; ++i)
        #pragma unroll
        for (int k = 0; k < 4; ++k)
            #pragma unroll
            for (int j = 0; j < 4; ++j)
                Gm[i][k][j] = 0.5f * GIa[i] * ((k == i ? dg[i][j] : 0.f)
                                             + (j == i ? dg[i][k] : 0.f)
                                             - (j == k ? dg[j][i] : 0.f));
    float T[4];
    #pragma unroll
    for (int m = 0; m < 4; ++m) {
        float s = 0.f;
        #pragma unroll
        for (int i = 0; i < 4; ++i) s += Gm[i][m][i];
        T[m] = s;
    }
    auto dGm = [&](int i, int k, int j, int l) -> float {
        const float P = (k == i ? dg[i][j] : 0.f) + (j == i ? dg[i][k] : 0.f) - (j == k ? dg[j][i] : 0.f);
        const float Q = (k == i ? dd(i, j, l) : 0.f) + (j == i ? dd(i, k, l) : 0.f) - (j == k ? dd(j, i, l) : 0.f);
        return 0.5f * (GIa[i] * Q - dg[i][l] * GIa[i] * GIa[i] * P);
    };

    float rc[4][4];
    #pragma unroll
    for (int j = 0; j < 4; ++j)
        #pragma unroll
        for (int k = 0; k < 4; ++k) {
            float t1 = 0.f, t2 = 0.f, t3 = 0.f, t4 = 0.f;
            #pragma unroll
            for (int m = 0; m < 4; ++m) t1 += Gm[m][j][k] * T[m];
            #pragma unroll
            for (int m = 0; m < 4; ++m)
                #pragma unroll
                for (int i = 0; i < 4; ++i) t2 += Gm[m][j][i] * Gm[i][m][k];
            #pragma unroll
            for (int i = 0; i < 4; ++i) { t3 += dGm(i, j, k, i); t4 += dGm(i, j, i, k); }
            rc[j][k] = t1 - t2 + t3 - t4;
        }

    const float R = -rc[0][0] + GI1 * rc[1][1] + GI2 * rc[2][2] + GI3 * rc[3][3];
    #pragma unroll
    for (int j = 0; j < 4; ++j) {
        f32x4 o;
        #pragma unroll
        for (int k = 0; k < 4; ++k)
            o[k] = GIa[j] * GIa[k] * rc[j][k] - ((j == k) ? 0.5f * R * GIa[j] : 0.f);
        reinterpret_cast<f32x4*>(out)[p * 4 + j] = o;
    }
}

extern "C" void kernel_launch(void* const* d_in, const int* in_sizes, int n_in,
                              void* d_out, int out_size, void* d_ws, size_t ws_size,
                              hipStream_t stream) {
    const float* coords = (const float*)d_in[0];
    const float* W1 = (const float*)d_in[1];
    const float* b1 = (const float*)d_in[2];
    const float* W2 = (const float*)d_in[3];
    const float* b2 = (const float*)d_in[4];
    const float* W3 = (const float*)d_in[5];
    const float* b3 = (const float*)d_in[6];
    const float* W4 = (const float*)d_in[7];
    const float* b4 = (const float*)d_in[8];
    const int B = in_sizes[0] / 4;

    hipLaunchKernelGGL(jet_kernel, dim3(NBLOCKS), dim3(BLOCK), 0, stream,
                       coords, W1, b1, W2, b2, W3, b3, W4,
                       (float*)d_ws, B);
    hipLaunchKernelGGL(einstein_epilogue, dim3((B + BLOCK - 1) / BLOCK), dim3(BLOCK), 0, stream,
                       coords, (const float*)d_ws, b4, (float*)d_out, B);
}

// Round 16
// 72.119 us; speedup vs baseline: 1.0179x; 1.0179x over previous
//
#include <hip/hip_runtime.h>

#define NBLOCKS 4096
#define WPB 4
#define BLOCK 256

typedef __attribute__((ext_vector_type(8))) short sh8;
typedef __attribute__((ext_vector_type(4))) float f32x4;

__device__ __forceinline__ float frcp(float x) { return __builtin_amdgcn_rcpf(x); }

__device__ __forceinline__ float fast_tanh(float x) {
    float e = __expf(2.f * x);
    return 1.f - 2.f * frcp(e + 1.f);
}

// swizzled bf16 index into a [rows][64] LDS array (row stride = 32 dwords).
__device__ __forceinline__ int zidx(int m, int u) {
    return (((m << 5) + (((u >> 1) ^ ((m & 7) << 2)))) << 1) + (u & 1);
}

__device__ __forceinline__ sh8 ldfrag(const unsigned short* base, int row, int g, int kt) {
    const int dw = (row << 5) + ((((kt << 4) + (g << 2))) ^ ((row & 7) << 2));
    return *(const sh8*)(base + (dw << 1));
}

__device__ __forceinline__ unsigned short rtn_bf16(float x) {
    unsigned u = __float_as_uint(x);
    u += 0x7FFFu + ((u >> 16) & 1u);
    return (unsigned short)(u >> 16);
}

__device__ __forceinline__ unsigned cvt_pk_bf16(float lo, float hi) {
    unsigned r;
    asm("v_cvt_pk_bf16_f32 %0, %1, %2" : "=v"(r) : "v"(lo), "v"(hi));
    return r;
}

__device__ __forceinline__ void wsplit(float x, unsigned short& h, unsigned short& l) {
    const unsigned ub = __float_as_uint(x);
    const unsigned hb = ub & 0xffff0000u;
    const float lf = x - __uint_as_float(hb);
    h = (unsigned short)(hb >> 16);
    l = (unsigned short)(__float_as_uint(lf) >> 16);
}

__device__ __forceinline__ void stage15s(unsigned short* zh, const float* z, int lane) {
    #pragma unroll
    for (int m = 0; m < 14; m += 2) {
        const unsigned r = cvt_pk_bf16(z[m], z[m + 1]);
        zh[zidx(m, lane)] = (unsigned short)r;
        zh[zidx(m + 1, lane)] = (unsigned short)(r >> 16);
    }
    zh[zidx(14, lane)] = (unsigned short)cvt_pk_bf16(z[14], z[14]);
}

__device__ __forceinline__ void jet_nl(const float* a, float bias, float* z) {
    const float a0v = a[0] + bias;
    const float y = fast_tanh(a0v);
    const float D = 1.f - y * y;
    const float m2 = -2.f * y * D;
    z[0] = y;
    z[1] = D * a[1]; z[2] = D * a[2]; z[3] = D * a[3]; z[4] = D * a[4];
    z[5] = D * a[5] + m2 * a[1] * a[1];
    z[6] = D * a[6] + m2 * a[1] * a[2];
    z[7] = D * a[7] + m2 * a[1] * a[3];
    z[8] = D * a[8] + m2 * a[1] * a[4];
    z[9] = D * a[9] + m2 * a[2] * a[2];
    z[10] = D * a[10] + m2 * a[2] * a[3];
    z[11] = D * a[11] + m2 * a[2] * a[4];
    z[12] = D * a[12] + m2 * a[3] * a[3];
    z[13] = D * a[13] + m2 * a[3] * a[4];
    z[14] = D * a[14] + m2 * a[4] * a[4];
}

#define WAITLDS asm volatile("" ::: "memory")

// ============ kernel 1: MLP jet pipeline -> 15 scalars/pt into ws ============
// PRECISION LEDGER: state/W2/W3 = single RNE bf16; W1 = f32; W4 = hi/lo bf16.
// absmax 6144 vs threshold 1.024e4 -- no further precision cuts.
// REVERT NOTE (R15): ds_read_b64_tr_b16 unit-major staging FAILED on HW
// (absmax 1.6e6) -- tr-read layout semantics differ from the assumed
// per-lane-vaddr + 32B-elem-stride model. This is the R13 structure (72 us),
// DS-pipe-bound by census; R14 registerization was neutral (occupancy offset).
__global__ __launch_bounds__(BLOCK, 4) void jet_kernel(
    const float* __restrict__ coords,
    const float* __restrict__ gW1, const float* __restrict__ gb1,
    const float* __restrict__ gW2, const float* __restrict__ gb2,
    const float* __restrict__ gW3, const float* __restrict__ gb3,
    const float* __restrict__ gW4,
    float* __restrict__ ws, int B)
{
    __shared__ __align__(16) unsigned short wlds[2][4096];
    __shared__ __align__(16) unsigned short w4lds[2048];
    __shared__ __align__(16) unsigned short zS[WPB][2048];

    const int wv = threadIdx.x >> 6;
    const int lane = threadIdx.x & 63;
    const int n15 = lane & 15;
    const int g = lane >> 4;

    unsigned short* zbase = zS[wv];
    float* cb = (float*)zbase;

    for (int e = threadIdx.x; e < 4096; e += BLOCK) {
        const int o = e & 63, i = e >> 6;
        const int ix = zidx(o, i);
        wlds[0][ix] = rtn_bf16(gW2[i * 64 + o]);
        wlds[1][ix] = rtn_bf16(gW3[i * 64 + o]);
    }
    #pragma unroll
    for (int kt = 0; kt < 2; ++kt) {
        sh8 bh, bl;
        #pragma unroll
        for (int e = 0; e < 8; ++e) {
            const float v = (n15 == 0) ? gW4[kt * 32 + g * 8 + e] : 0.f;
            unsigned short h, l;
            wsplit(v, h, l);
            bh[e] = (short)h;
            bl[e] = (short)l;
        }
        *(sh8*)(w4lds + kt * 512 + (lane << 3)) = bh;
        *(sh8*)(w4lds + (2 + kt) * 512 + (lane << 3)) = bl;
    }
    __syncthreads();
    // A-row 15 garbage (cb alias residue) confined to C row 15: never read.

    const float w1c0 = gW1[0 * 64 + lane];
    const float w1c1 = gW1[1 * 64 + lane];
    const float w1c2 = gW1[2 * 64 + lane];
    const float w1c3 = gW1[3 * 64 + lane];
    const float b1c = gb1[lane], b2c = gb2[lane], b3c = gb3[lane];

    const int wid = blockIdx.x * WPB + wv;
    const int nw = NBLOCKS * WPB;

    for (int p = 2 * wid; p < B; p += 2 * nw) {
        float4 c4[2];
        c4[0] = reinterpret_cast<const float4*>(coords)[p];
        c4[1] = reinterpret_cast<const float4*>(coords)[p + 1];

        #pragma unroll
        for (int pt = 0; pt < 2; ++pt) {
            float z[15];
            const float u = b1c + c4[pt].x * w1c0 + c4[pt].y * w1c1 + c4[pt].z * w1c2 + c4[pt].w * w1c3;
            const float y = fast_tanh(u);
            const float D = 1.f - y * y;
            const float m2 = -2.f * y * D;
            z[0] = y;
            z[1] = D * w1c0; z[2] = D * w1c1; z[3] = D * w1c2; z[4] = D * w1c3;
            z[5] = m2 * w1c0 * w1c0; z[6] = m2 * w1c0 * w1c1; z[7] = m2 * w1c0 * w1c2; z[8] = m2 * w1c0 * w1c3;
            z[9] = m2 * w1c1 * w1c1; z[10] = m2 * w1c1 * w1c2; z[11] = m2 * w1c1 * w1c3;
            z[12] = m2 * w1c2 * w1c2; z[13] = m2 * w1c2 * w1c3; z[14] = m2 * w1c3 * w1c3;
            stage15s(zbase + pt * 1024, z, lane);
        }
        WAITLDS;

        #pragma unroll
        for (int LL = 0; LL < 2; ++LL) {
            const unsigned short* wl = wlds[LL];
            sh8 A0[2], A1[2];
            #pragma unroll
            for (int pt = 0; pt < 2; ++pt) {
                A0[pt] = ldfrag(zbase + pt * 1024, n15, g, 0);
                A1[pt] = ldfrag(zbase + pt * 1024, n15, g, 1);
            }
            WAITLDS;
            f32x4 acc[2][4];
            #pragma unroll
            for (int nt = 0; nt < 4; ++nt) {
                const sh8 B0 = ldfrag(wl, nt * 16 + n15, g, 0);
                const sh8 B1 = ldfrag(wl, nt * 16 + n15, g, 1);
                #pragma unroll
                for (int pt = 0; pt < 2; ++pt) {
                    f32x4 a0 = {0.f, 0.f, 0.f, 0.f};
                    a0 = __builtin_amdgcn_mfma_f32_16x16x32_bf16(A0[pt], B0, a0, 0, 0, 0);
                    a0 = __builtin_amdgcn_mfma_f32_16x16x32_bf16(A1[pt], B1, a0, 0, 0, 0);
                    acc[pt][nt] = a0;
                }
            }
            float z0[15], z1[15];
            {
                #pragma unroll
                for (int nt = 0; nt < 4; ++nt) {
                    const int u = nt * 16 + n15;
                    *(f32x4*)(cb + u * 16 + ((g << 2) ^ (u & 12))) = acc[0][nt];
                }
                WAITLDS;
                float a[15];
                #pragma unroll
                for (int c = 0; c < 4; ++c) {
                    const f32x4 r = *(const f32x4*)(cb + lane * 16 + ((c << 2) ^ (lane & 12)));
                    #pragma unroll
                    for (int t = 0; t < 4; ++t)
                        if (c * 4 + t < 15) a[c * 4 + t] = r[t];
                }
                WAITLDS;
                jet_nl(a, LL ? b3c : b2c, z0);
            }
            {
                #pragma unroll
                for (int nt = 0; nt < 4; ++nt) {
                    const int u = nt * 16 + n15;
                    *(f32x4*)(cb + u * 16 + ((g << 2) ^ (u & 12))) = acc[1][nt];
                }
                WAITLDS;
                float a[15];
                #pragma unroll
                for (int c = 0; c < 4; ++c) {
                    const f32x4 r = *(const f32x4*)(cb + lane * 16 + ((c << 2) ^ (lane & 12)));
                    #pragma unroll
                    for (int t = 0; t < 4; ++t)
                        if (c * 4 + t < 15) a[c * 4 + t] = r[t];
                }
                WAITLDS;
                jet_nl(a, LL ? b3c : b2c, z1);
            }
            stage15s(zbase, z0, lane);
            stage15s(zbase + 1024, z1, lane);
            WAITLDS;
        }

        // final layer (64 -> 1) as MFMA reduce; jets land in lanes n15==0
        {
            const sh8 Bh0 = *(const sh8*)(w4lds + 0 * 512 + (lane << 3));
            const sh8 Bh1 = *(const sh8*)(w4lds + 1 * 512 + (lane << 3));
            const sh8 Bw0 = *(const sh8*)(w4lds + 2 * 512 + (lane << 3));
            const sh8 Bw1 = *(const sh8*)(w4lds + 3 * 512 + (lane << 3));
            #pragma unroll
            for (int pt = 0; pt < 2; ++pt) {
                const sh8 A0 = ldfrag(zbase + pt * 1024, n15, g, 0);
                const sh8 A1 = ldfrag(zbase + pt * 1024, n15, g, 1);
                f32x4 r = {0.f, 0.f, 0.f, 0.f};
                r = __builtin_amdgcn_mfma_f32_16x16x32_bf16(A0, Bh0, r, 0, 0, 0);
                r = __builtin_amdgcn_mfma_f32_16x16x32_bf16(A1, Bh1, r, 0, 0, 0);
                r = __builtin_amdgcn_mfma_f32_16x16x32_bf16(A0, Bw0, r, 0, 0, 0);
                r = __builtin_amdgcn_mfma_f32_16x16x32_bf16(A1, Bw1, r, 0, 0, 0);
                // row m = g*4+reg, col 0 = lanes n15==0: 4 lanes store 4 jets each
                if (n15 == 0)
                    reinterpret_cast<f32x4*>(ws)[(p + pt) * 4 + g] = r;
            }
        }
        WAITLDS;   // frag reads ordered before next iteration's stage15s clobbers
    }
}

// ============ kernel 2: per-point Einstein epilogue, all-register ============
__global__ void einstein_epilogue(
    const float* __restrict__ coords,
    const float* __restrict__ ws,
    const float* __restrict__ gb4,
    float* __restrict__ out, int B)
{
    const int p = blockIdx.x * blockDim.x + threadIdx.x;
    if (p >= B) return;
    const float4 c4 = reinterpret_cast<const float4*>(coords)[p];
    const float cr = c4.y, cth = c4.z;
    const f32x4 r0 = reinterpret_cast<const f32x4*>(ws)[p * 4 + 0];
    const f32x4 r1 = reinterpret_cast<const f32x4*>(ws)[p * 4 + 1];
    const f32x4 r2 = reinterpret_cast<const f32x4*>(ws)[p * 4 + 2];
    const f32x4 r3 = reinterpret_cast<const f32x4*>(ws)[p * 4 + 3];
    const float f = r0[0] + gb4[0];
    float fj[4] = {r0[1], r0[2], r0[3], r1[0]};
    float fk[4][4];
    fk[0][0] = r1[1]; fk[0][1] = fk[1][0] = r1[2]; fk[0][2] = fk[2][0] = r1[3]; fk[0][3] = fk[3][0] = r2[0];
    fk[1][1] = r2[1]; fk[1][2] = fk[2][1] = r2[2]; fk[1][3] = fk[3][1] = r2[3];
    fk[2][2] = r3[0]; fk[2][3] = fk[3][2] = r3[1]; fk[3][3] = r3[2];

    float S, C;
    __sincosf(cth, &S, &C);
    const float E = __expf(f);
    const float r2v = cr * cr, S2 = S * S;
    const float GI1 = frcp(E), GI2 = frcp(r2v), GI3 = GI2 * frcp(S2);
    const float GIa[4] = {-1.f, GI1, GI2, GI3};

    float dg[4][4] = {};
    #pragma unroll
    for (int b = 0; b < 4; ++b) dg[1][b] = E * fj[b];
    dg[2][1] = 2.f * cr;
    dg[3][1] = 2.f * cr * S2;
    dg[3][2] = 2.f * r2v * S * C;
    const float ddrr3 = 2.f * S2, ddrth3 = 4.f * cr * S * C, ddthth3 = 2.f * r2v * (C * C - S2);

    auto dd = [&](int a, int b, int l) -> float {
        if (a == 1) return E * (fj[b] * fj[l] + fk[b][l]);
        if (a == 2) return (b == 1 && l == 1) ? 2.f : 0.f;
        if (a == 3) {
            if (b == 1 && l == 1) return ddrr3;
            if ((b == 1 && l == 2) || (b == 2 && l == 1)) return ddrth3;
            if (b == 2 && l == 2) return ddthth3;
        }
        return 0.f;
    };

    float Gm[4][4][4];
    #pragma unroll
    for (int i = 0; i < 4; ++i)
        #pragma unroll
        for (int k = 0; k < 4; ++k)
            #pragma unroll
            for (int j = 0; j < 4; ++j)
                Gm[i][k][j] = 0.5f * GIa[i] * ((k == i ? dg[i][j] : 0.f)
                                             + (j == i ? dg[i][k] : 0.f)
                                             - (j == k ? dg[j][i] : 0.f));
    float T[4];
    #pragma unroll
    for (int m = 0; m < 4; ++m) {
        float s = 0.f;
        #pragma unroll
        for (int i = 0; i < 4; ++i) s += Gm[i][m][i];
        T[m] = s;
    }
    auto dGm = [&](int i, int k, int j, int l) -> float {
        const float P = (k == i ? dg[i][j] : 0.f) + (j == i ? dg[i][k] : 0.f) - (j == k ? dg[j][i] : 0.f);
        const float Q = (k == i ? dd(i, j, l) : 0.f) + (j == i ? dd(i, k, l) : 0.f) - (j == k ? dd(j, i, l) : 0.f);
        return 0.5f * (GIa[i] * Q - dg[i][l] * GIa[i] * GIa[i] * P);
    };

    float rc[4][4];
    #pragma unroll
    for (int j = 0; j < 4; ++j)
        #pragma unroll
        for (int k = 0; k < 4; ++k) {
            float t1 = 0.f, t2 = 0.f, t3 = 0.f, t4 = 0.f;
            #pragma unroll
            for (int m = 0; m < 4; ++m) t1 += Gm[m][j][k] * T[m];
            #pragma unroll
            for (int m = 0; m < 4; ++m)
                #pragma unroll
                for (int i = 0; i < 4; ++i) t2 += Gm[m][j][i] * Gm[i][m][k];
            #pragma unroll
            for (int i = 0; i < 4; ++i) { t3 += dGm(i, j, k, i); t4 += dGm(i, j, i, k); }
            rc[j][k] = t1 - t2 + t3 - t4;
        }

    const float R = -rc[0][0] + GI1 * rc[1][1] + GI2 * rc[2][2] + GI3 * rc[3][3];
    #pragma unroll
    for (int j = 0; j < 4; ++j) {
        f32x4 o;
        #pragma unroll
        for (int k = 0; k < 4; ++k)
            o[k] = GIa[j] * GIa[k] * rc[j][k] - ((j == k) ? 0.5f * R * GIa[j] : 0.f);
        reinterpret_cast<f32x4*>(out)[p * 4 + j] = o;
    }
}

extern "C" void kernel_launch(void* const* d_in, const int* in_sizes, int n_in,
                              void* d_out, int out_size, void* d_ws, size_t ws_size,
                              hipStream_t stream) {
    const float* coords = (const float*)d_in[0];
    const float* W1 = (const float*)d_in[1];
    const float* b1 = (const float*)d_in[2];
    const float* W2 = (const float*)d_in[3];
    const float* b2 = (const float*)d_in[4];
    const float* W3 = (const float*)d_in[5];
    const float* b3 = (const float*)d_in[6];
    const float* W4 = (const float*)d_in[7];
    const float* b4 = (const float*)d_in[8];
    const int B = in_sizes[0] / 4;

    hipLaunchKernelGGL(jet_kernel, dim3(NBLOCKS), dim3(BLOCK), 0, stream,
                       coords, W1, b1, W2, b2, W3, b3, W4,
                       (float*)d_ws, B);
    hipLaunchKernelGGL(einstein_epilogue, dim3((B + BLOCK - 1) / BLOCK), dim3(BLOCK), 0, stream,
                       coords, (const float*)d_ws, b4, (float*)d_out, B);
}